// Round 3
// baseline (2031.463 us; speedup 1.0000x reference)
//
#include <hip/hip_runtime.h>
#include <cstdint>
#include <cstddef>

#define B_DIM 16
#define C_DIM 768
#define NPIX  1024
#define NTOT  (B_DIM * NPIX)   // 16384 columns (b*1024 + n)

// ---------------------------------------------------------------------------
// Branch GEMM + BN + LIF spike, bit-matching numpy float32 naive semantics:
//   y[o,j]   = sum_c fl32( y + fl32(w[o,c]*xs[c,j]) )   (ascending c, mul+add)
//   inv[o]   = g[o] / sqrtf(var[o] + 1e-5f)
//   ybn      = fl32( fl32(y*inv) + fl32(b[o] - fl32(m[o]*inv)) )
//   spike    = ybn >= 2.0f          ( == (ybn/2 - 1 >= 0) exactly in fp32 )
// Contraction disabled so mul/add stay separately rounded like numpy.
// ---------------------------------------------------------------------------
__global__ __launch_bounds__(256) void branch_gemm_spike(
    const float* __restrict__ x, const float* __restrict__ w,
    const float* __restrict__ gamma, const float* __restrict__ beta,
    const float* __restrict__ mean, const float* __restrict__ var,
    unsigned char* __restrict__ s_out)
{
#pragma clang fp contract(off)
    __shared__ float As[16][132];
    __shared__ float Bs[16][132];
    const int tileN = blockIdx.x * 128;
    const int tileM = blockIdx.y * 128;
    const int tid = threadIdx.x;
    const int tx = tid & 15, ty = tid >> 4;
    const int b  = tileN / NPIX;          // tiles are aligned: one batch per tile
    const int n0 = tileN - b * NPIX;
    const float* xb = x + (size_t)b * C_DIM * NPIX + n0;

    float acc[8][8];
#pragma unroll
    for (int i = 0; i < 8; ++i)
#pragma unroll
        for (int j = 0; j < 8; ++j) acc[i][j] = 0.0f;

    for (int k0 = 0; k0 < C_DIM; k0 += 16) {
#pragma unroll
        for (int i = 0; i < 8; ++i) {
            int idx = tid + i * 256;     // 0..2047
            int r  = idx >> 4;           // 0..127  (row within M tile)
            int kk = idx & 15;
            As[kk][r] = w[(size_t)(tileM + r) * C_DIM + (k0 + kk)];
        }
#pragma unroll
        for (int i = 0; i < 8; ++i) {
            int idx = tid + i * 256;
            int kk = idx >> 7;           // 0..15
            int j  = idx & 127;
            float v = xb[(size_t)(k0 + kk) * NPIX + j];
            Bs[kk][j] = (v >= 2.0f) ? 1.0f : 0.0f;
        }
        __syncthreads();
        // ascending c within the tile: kk = 0..15 (c = k0 + kk)
#pragma unroll
        for (int kk = 0; kk < 16; ++kk) {
            float a[8], bb[8];
#pragma unroll
            for (int i = 0; i < 8; ++i) a[i] = As[kk][ty * 8 + i];
#pragma unroll
            for (int j = 0; j < 8; ++j) bb[j] = Bs[kk][tx * 8 + j];
#pragma unroll
            for (int i = 0; i < 8; ++i)
#pragma unroll
                for (int j = 0; j < 8; ++j) {
                    float p = a[i] * bb[j];     // fl32 mul (contract off)
                    acc[i][j] = acc[i][j] + p;  // fl32 add
                }
        }
        __syncthreads();
    }

#pragma unroll
    for (int i = 0; i < 8; ++i) {
        int o = tileM + ty * 8 + i;
        float invv = gamma[o] / sqrtf(var[o] + 1e-5f);  // np: g / sqrt(v + eps)
        float t1   = mean[o] * invv;                    // np: m * inv
        float bias = beta[o] - t1;                      // np: b - m*inv
        size_t base = (size_t)o * NTOT + tileN + tx * 8;
#pragma unroll
        for (int j = 0; j < 8; ++j) {
            float t3  = acc[i][j] * invv;               // np: y * inv
            float ybn = t3 + bias;                      // np: + bias
            s_out[base + j] = (ybn >= 2.0f) ? (unsigned char)1 : (unsigned char)0;
        }
    }
}

// ---------------------------------------------------------------------------
// kv mask: mask[b][c] = OR_n (s_k[c][b*1024+n] & s_v[c][b*1024+n])
// (sum over tokens of binary products is an exact integer in f32;
//  lif(kv, 0.5) == count >= 1 exactly)
// ---------------------------------------------------------------------------
__global__ __launch_bounds__(256) void kv_mask_kernel(
    const unsigned char* __restrict__ sk, const unsigned char* __restrict__ sv,
    unsigned char* __restrict__ mask)
{
    const int blk = blockIdx.x;            // 0 .. B*C-1
    const int b = blk / C_DIM;
    const int c = blk - b * C_DIM;
    const size_t base = (size_t)c * NTOT + (size_t)b * NPIX;
    const int tid = threadIdx.x;
    uchar4 kk = *(const uchar4*)(sk + base + tid * 4);
    uchar4 vv = *(const uchar4*)(sv + base + tid * 4);
    int local = (kk.x & vv.x) | (kk.y & vv.y) | (kk.z & vv.z) | (kk.w & vv.w);
    __shared__ int f;
    if (tid == 0) f = 0;
    __syncthreads();
    if (local) f = 1;                      // benign race, deterministic value
    __syncthreads();
    if (tid == 0) mask[b * C_DIM + c] = (unsigned char)f;
}

// ---------------------------------------------------------------------------
// Final projection GEMM + bias + BN + identity (no threshold -> fp32+FMA ample):
// out[b,p,n] = (sum_o wp[p,o]*(s_q[o][j]&mask[b][o]) + bp[p])*inv[p]
//              + (beta[p]-mean[p]*inv[p]) + x[b,p,n]
// ---------------------------------------------------------------------------
__global__ __launch_bounds__(256) void final_gemm(
    const float* __restrict__ x, const unsigned char* __restrict__ sq,
    const unsigned char* __restrict__ mask,
    const float* __restrict__ wp, const float* __restrict__ bp,
    const float* __restrict__ gamma, const float* __restrict__ beta,
    const float* __restrict__ mean, const float* __restrict__ var,
    float* __restrict__ out)
{
    __shared__ float As[16][132];
    __shared__ float Bs[16][132];
    const int tileN = blockIdx.x * 128;
    const int tileM = blockIdx.y * 128;
    const int tid = threadIdx.x;
    const int tx = tid & 15, ty = tid >> 4;
    const int b  = tileN / NPIX;
    const int n0 = tileN - b * NPIX;

    float acc[8][8];
#pragma unroll
    for (int i = 0; i < 8; ++i)
#pragma unroll
        for (int j = 0; j < 8; ++j) acc[i][j] = 0.0f;

    for (int k0 = 0; k0 < C_DIM; k0 += 16) {
#pragma unroll
        for (int i = 0; i < 8; ++i) {
            int idx = tid + i * 256;
            int r  = idx >> 4;
            int kk = idx & 15;
            As[kk][r] = wp[(size_t)(tileM + r) * C_DIM + (k0 + kk)];
        }
#pragma unroll
        for (int i = 0; i < 8; ++i) {
            int idx = tid + i * 256;
            int kk = idx >> 7;
            int j  = idx & 127;
            int o  = k0 + kk;
            unsigned char s = sq[(size_t)o * NTOT + tileN + j];
            unsigned char m = mask[b * C_DIM + o];
            Bs[kk][j] = (s & m) ? 1.0f : 0.0f;
        }
        __syncthreads();
#pragma unroll
        for (int kk = 0; kk < 16; ++kk) {
            float a[8], bb[8];
#pragma unroll
            for (int i = 0; i < 8; ++i) a[i] = As[kk][ty * 8 + i];
#pragma unroll
            for (int j = 0; j < 8; ++j) bb[j] = Bs[kk][tx * 8 + j];
#pragma unroll
            for (int i = 0; i < 8; ++i)
#pragma unroll
                for (int j = 0; j < 8; ++j)
                    acc[i][j] = fmaf(a[i], bb[j], acc[i][j]);
        }
        __syncthreads();
    }

#pragma unroll
    for (int i = 0; i < 8; ++i) {
        int p = tileM + ty * 8 + i;
        float invv = gamma[p] / sqrtf(var[p] + 1e-5f);
        float bias = beta[p] - mean[p] * invv;
        float bpp  = bp[p];
        size_t rowbase = (size_t)b * C_DIM * NPIX + (size_t)p * NPIX + n0 + tx * 8;
#pragma unroll
        for (int j = 0; j < 8; ++j) {
            float ypre = acc[i][j] + bpp;
            float val  = ypre * invv + bias + x[rowbase + j];
            out[rowbase + j] = val;
        }
    }
}

extern "C" void kernel_launch(void* const* d_in, const int* in_sizes, int n_in,
                              void* d_out, int out_size, void* d_ws, size_t ws_size,
                              hipStream_t stream) {
    const float* x  = (const float*)d_in[0];
    const float* wq = (const float*)d_in[1];
    const float* qg = (const float*)d_in[2];
    const float* qb = (const float*)d_in[3];
    const float* qm = (const float*)d_in[4];
    const float* qv = (const float*)d_in[5];
    const float* wk = (const float*)d_in[6];
    const float* kg = (const float*)d_in[7];
    const float* kb = (const float*)d_in[8];
    const float* km = (const float*)d_in[9];
    const float* kvv= (const float*)d_in[10];
    const float* wv = (const float*)d_in[11];
    const float* vg = (const float*)d_in[12];
    const float* vb = (const float*)d_in[13];
    const float* vm = (const float*)d_in[14];
    const float* vv = (const float*)d_in[15];
    const float* wp = (const float*)d_in[16];
    const float* bp = (const float*)d_in[17];
    const float* pg = (const float*)d_in[18];
    const float* pb = (const float*)d_in[19];
    const float* pm = (const float*)d_in[20];
    const float* pv = (const float*)d_in[21];

    const size_t SZ = (size_t)C_DIM * NTOT;   // 12,582,912 bytes per spike plane
    unsigned char* sq   = (unsigned char*)d_ws;
    unsigned char* sk   = sq + SZ;
    unsigned char* sv   = sk + SZ;
    unsigned char* mask = sv + SZ;            // B*C = 12288 bytes

    dim3 grid(NTOT / 128, C_DIM / 128);       // (128, 6)
    branch_gemm_spike<<<grid, 256, 0, stream>>>(x, wq, qg, qb, qm, qv, sq);
    branch_gemm_spike<<<grid, 256, 0, stream>>>(x, wk, kg, kb, km, kvv, sk);
    branch_gemm_spike<<<grid, 256, 0, stream>>>(x, wv, vg, vb, vm, vv, sv);
    kv_mask_kernel<<<B_DIM * C_DIM, 256, 0, stream>>>(sk, sv, mask);
    final_gemm<<<grid, 256, 0, stream>>>(x, sq, mask, wp, bp, pg, pb, pm, pv, (float*)d_out);
}

// Round 4
// 768.528 us; speedup vs baseline: 2.6433x; 2.6433x over previous
//
#include <hip/hip_runtime.h>
#include <cstdint>
#include <cstddef>

#define C_DIM 768
#define NPIX  1024
#define B_DIM 16
#define NTOT  16384
#define KT_N  24      // 768/32 K-tiles
#define MT_N  6       // 768/128 M-tiles
#define JT_N  128     // 16384/128 N-tiles
#define TAU   2.0e-3f
#define CAP_REC 262144

typedef __attribute__((ext_vector_type(8))) short short8;
typedef __attribute__((ext_vector_type(4))) float f32x4;

// ---------------------------------------------------------------------------
// async global->LDS 16B copy (per-lane global src, linear LDS dest)
// ---------------------------------------------------------------------------
__device__ __forceinline__ void gload16(const void* g, void* l) {
    __builtin_amdgcn_global_load_lds(
        (const __attribute__((address_space(1))) unsigned int*)g,
        (__attribute__((address_space(3))) unsigned int*)l, 16, 0, 0);
}

// ---------------------------------------------------------------------------
// Weight split: w(f32) -> 3 bf16 planes (hi/lo/lo2, truncation => exact sum),
// stored in A-blob tile layout: plane[s][tile=kt*6+mt][kb(4)][m(128)][e(8)]
// so GEMM staging is a linear 8KB copy and fragment reads are 16B ds_read.
// ---------------------------------------------------------------------------
__global__ __launch_bounds__(256) void prep_weights(
    const float* __restrict__ w0, const float* __restrict__ w1,
    const float* __restrict__ w2, const float* __restrict__ w3,
    short* __restrict__ p0, short* __restrict__ p1,
    short* __restrict__ p2, short* __restrict__ p3)
{
    const int tile = blockIdx.x;          // kt*6 + mt
    const int set  = blockIdx.y;
    const int kt = tile / MT_N, mt = tile % MT_N;
    const float* w = set == 0 ? w0 : set == 1 ? w1 : set == 2 ? w2 : w3;
    short* pl      = set == 0 ? p0 : set == 1 ? p1 : set == 2 ? p2 : p3;
    const int PLANE = C_DIM * C_DIM;      // shorts per split plane (tiled)
#pragma unroll
    for (int i = 0; i < 2; ++i) {
        int q = threadIdx.x + i * 256;    // chunk (kb, m)
        int kb = q >> 7, m = q & 127;
        int o = mt * 128 + m;
        int cbase = kt * 32 + kb * 8;
        short8 H, L, L2;
#pragma unroll
        for (int e = 0; e < 8; ++e) {
            float wv = w[(size_t)o * C_DIM + cbase + e];
            uint32_t b0 = __float_as_uint(wv);
            float hi = __uint_as_float(b0 & 0xFFFF0000u);
            float r1 = wv - hi;                       // exact
            uint32_t b1 = __float_as_uint(r1);
            float lo = __uint_as_float(b1 & 0xFFFF0000u);
            float r2 = r1 - lo;                       // exact, fits 8 bits
            uint32_t b2 = __float_as_uint(r2);
            H[e]  = (short)(b0 >> 16);
            L[e]  = (short)(b1 >> 16);
            L2[e] = (short)(b2 >> 16);
        }
        size_t base = (size_t)tile * 4096 + (size_t)q * 8;
        *(short8*)(pl + base)             = H;
        *(short8*)(pl + PLANE + base)     = L;
        *(short8*)(pl + 2 * PLANE + base) = L2;
    }
}

// ---------------------------------------------------------------------------
// Input spikes xs = (x >= 2) as bf16 {0,1}, B-blob layout:
// xs[tile=jt*24+kt][kb(4)][col(128)][e(8)]
// ---------------------------------------------------------------------------
__global__ __launch_bounds__(256) void prep_spikes(
    const float* __restrict__ x, short* __restrict__ xs)
{
    const int jt = blockIdx.x;            // 0..127
    const int kt = blockIdx.y;            // 0..23
    const int b  = jt >> 3;
    const int n0 = (jt & 7) * 128;
    const int c0 = kt * 32;
#pragma unroll
    for (int i = 0; i < 2; ++i) {
        int q = threadIdx.x + i * 256;    // (kb, col)
        int kb = q >> 7, col = q & 127;
        short8 sv;
#pragma unroll
        for (int e = 0; e < 8; ++e) {
            float xv = x[((size_t)b * C_DIM + (c0 + kb * 8 + e)) * NPIX + n0 + col];
            sv[e] = (xv >= 2.0f) ? (short)0x3F80 : (short)0;
        }
        *(short8*)(xs + (size_t)(jt * KT_N + kt) * 4096 + (size_t)q * 8) = sv;
    }
}

// ---------------------------------------------------------------------------
// Branch GEMM via MFMA (3-split bf16, exact representation):
//   acc[o,j] = sum_c (hi+lo+lo2)(w[o,c]) * xs[c,j]
// Epilogue: BN affine + spike; borderline (|ybn-2|<TAU) recorded for pass-2
// numpy-bit-exact re-resolution. Output written as spike B-blob (bf16 {0,1}).
// ---------------------------------------------------------------------------
__global__ __launch_bounds__(256) void branch_mfma(
    const short* __restrict__ wblob, const short* __restrict__ xsblob,
    const float* __restrict__ gamma, const float* __restrict__ beta,
    const float* __restrict__ mean, const float* __restrict__ var,
    short* __restrict__ sblob,
    unsigned int* __restrict__ cnt, unsigned int* __restrict__ recs,
    int plane_id)
{
    __shared__ short stage[16384];   // A_hi|A_lo|A_lo2 (3*8KB) + B (8KB)
    const int jt = blockIdx.x, mt = blockIdx.y;
    const int tid = threadIdx.x;
    const int lane = tid & 63, wv_ = tid >> 6;
    const int wr = wv_ >> 1, wc = wv_ & 1;       // 2x2 waves, 64x64 each
    const int lr = lane & 15, kb = lane >> 4;
    const int PLANE = C_DIM * C_DIM;

    f32x4 acc[4][4];
#pragma unroll
    for (int a = 0; a < 4; ++a)
#pragma unroll
        for (int b2 = 0; b2 < 4; ++b2) acc[a][b2] = (f32x4){0.f, 0.f, 0.f, 0.f};

    for (int kt = 0; kt < KT_N; ++kt) {
        const short* Abase = wblob + (size_t)(kt * MT_N + mt) * 4096;
        const short* Bbase = xsblob + (size_t)(jt * KT_N + kt) * 4096;
#pragma unroll
        for (int i = 0; i < 8; ++i) {
            int chunk = tid + i * 256;            // 0..2047
            const short* src;
            if (chunk < 1536) {
                int s = chunk >> 9;
                src = Abase + (size_t)s * PLANE + (size_t)(chunk - s * 512) * 8;
            } else {
                src = Bbase + (size_t)(chunk - 1536) * 8;
            }
            gload16(src, &stage[chunk * 8]);
        }
        __syncthreads();
        short8 bfr[4];
#pragma unroll
        for (int fn = 0; fn < 4; ++fn)
            bfr[fn] = *(const short8*)&stage[12288 + kb * 1024 + (wc * 64 + fn * 16 + lr) * 8];
#pragma unroll
        for (int s = 0; s < 3; ++s)
#pragma unroll
            for (int fm = 0; fm < 4; ++fm) {
                short8 a = *(const short8*)&stage[s * 4096 + kb * 1024 + (wr * 64 + fm * 16 + lr) * 8];
#pragma unroll
                for (int fn = 0; fn < 4; ++fn)
                    acc[fm][fn] = __builtin_amdgcn_mfma_f32_16x16x32_bf16(
                        a, bfr[fn], acc[fm][fn], 0, 0, 0);
            }
        __syncthreads();
    }

    // ---- epilogue: BN + spike + band records, via LDS u8 tile [128][132]
    unsigned char* sm = (unsigned char*)stage;
    const int rbase = (lane >> 4) * 4;
#pragma unroll
    for (int fm = 0; fm < 4; ++fm)
#pragma unroll
        for (int fn = 0; fn < 4; ++fn)
#pragma unroll
            for (int r = 0; r < 4; ++r) {
                int ml = wr * 64 + fm * 16 + rbase + r;
                int nl = wc * 64 + fn * 16 + lr;
                int o = mt * 128 + ml;
                float invv = gamma[o] / sqrtf(var[o] + 1e-5f);
                float bias = beta[o] - mean[o] * invv;
                float ybn = acc[fm][fn][r] * invv + bias;
                sm[ml * 132 + nl] = (ybn >= 2.0f) ? 1 : 0;
                if (fabsf(ybn - 2.0f) < TAU) {
                    unsigned int idx = atomicAdd(cnt, 1u);
                    if (idx < CAP_REC) {
                        int j = jt * 128 + nl;
                        recs[idx] = ((unsigned)plane_id << 24) | ((unsigned)o << 14) | (unsigned)j;
                    }
                }
            }
    __syncthreads();
    // ---- write spike blob (B-operand layout for downstream kernels)
#pragma unroll
    for (int i = 0; i < 8; ++i) {
        int q = tid + i * 256;                    // (kti, kb2, col)
        int kti = q >> 9, rem = q & 511;
        int kb2 = rem >> 7, col = rem & 127;
        short8 vblk;
#pragma unroll
        for (int e = 0; e < 8; ++e)
            vblk[e] = sm[(kti * 32 + kb2 * 8 + e) * 132 + col] ? (short)0x3F80 : (short)0;
        *(short8*)(sblob + (size_t)(jt * KT_N + mt * 4 + kti) * 4096 + (size_t)rem * 8) = vblk;
    }
}

// ---------------------------------------------------------------------------
// Pass-2 fixup: bit-exact numpy fp32 recompute of borderline spikes.
// Products in parallel (exact for {0,1} activations), serial ascending
// unfused adds by one lane, contraction off.
// ---------------------------------------------------------------------------
__global__ __launch_bounds__(256) void fixup(
    const float* __restrict__ x,
    const float* __restrict__ wq, const float* __restrict__ wk, const float* __restrict__ wv,
    const float* __restrict__ qg, const float* __restrict__ qb, const float* __restrict__ qm, const float* __restrict__ qv,
    const float* __restrict__ kg, const float* __restrict__ kb2, const float* __restrict__ km, const float* __restrict__ kvr,
    const float* __restrict__ vg, const float* __restrict__ vb, const float* __restrict__ vm, const float* __restrict__ vv,
    short* __restrict__ sq, short* __restrict__ sk, short* __restrict__ sv,
    const unsigned int* __restrict__ cnt, const unsigned int* __restrict__ recs)
{
#pragma clang fp contract(off)
    __shared__ float pl[C_DIM];
    unsigned int count = *cnt; if (count > CAP_REC) count = CAP_REC;
    for (unsigned int r = blockIdx.x; r < count; r += gridDim.x) {
        unsigned int rec = recs[r];
        int plane = rec >> 24, o = (rec >> 14) & 1023, j = rec & 16383;
        int b = j >> 10, n = j & 1023;
        const float* w = plane == 0 ? wq : plane == 1 ? wk : wv;
        for (int c = threadIdx.x; c < C_DIM; c += 256) {
            float xv = x[((size_t)b * C_DIM + c) * NPIX + n];
            pl[c] = (xv >= 2.0f) ? w[(size_t)o * C_DIM + c] : 0.0f;
        }
        __syncthreads();
        if (threadIdx.x == 0) {
            float s = 0.0f;
#pragma unroll 1
            for (int c = 0; c < C_DIM; ++c) s = s + pl[c];
            const float* g  = plane == 0 ? qg : plane == 1 ? kg : vg;
            const float* be = plane == 0 ? qb : plane == 1 ? kb2 : vb;
            const float* me = plane == 0 ? qm : plane == 1 ? km : vm;
            const float* va = plane == 0 ? qv : plane == 1 ? kvr : vv;
            float invv = g[o] / sqrtf(va[o] + 1e-5f);
            float t1 = me[o] * invv;
            float bias = be[o] - t1;
            float t3 = s * invv;
            float ybn = t3 + bias;
            short spv = (ybn >= 2.0f) ? (short)0x3F80 : (short)0;
            short* blob = plane == 0 ? sq : plane == 1 ? sk : sv;
            int jt = j >> 7, col = j & 127, kt = o >> 5, kbl = (o & 31) >> 3, e = o & 7;
            blob[(size_t)(jt * KT_N + kt) * 4096 + kbl * 1024 + col * 8 + e] = spv;
        }
        __syncthreads();
    }
}

// ---------------------------------------------------------------------------
// mask[b][c] = OR_n (sk & sv)  (exact: lif(sum, 0.5) == count>=1)
// ---------------------------------------------------------------------------
__global__ __launch_bounds__(256) void kv_mask_blob(
    const short* __restrict__ sk, const short* __restrict__ sv,
    short* __restrict__ mask)
{
    const int kt = blockIdx.x, b = blockIdx.y;
    const int t = threadIdx.x;
    const int kb = t >> 6;
    __shared__ unsigned int macc[4][8];
    if (t < 32) macc[t >> 3][t & 7] = 0;
    __syncthreads();
    unsigned int acc[8];
#pragma unroll
    for (int e = 0; e < 8; ++e) acc[e] = 0;
    for (int i = 0; i < 16; ++i) {
        int q = t * 16 + i;
        int pos = q & 1023;
        int jti = pos >> 7, col = pos & 127;
        size_t off = (size_t)((b * 8 + jti) * KT_N + kt) * 4096 + kb * 1024 + (size_t)col * 8;
        const uint32_t* kp = (const uint32_t*)(sk + off);
        const uint32_t* vp = (const uint32_t*)(sv + off);
#pragma unroll
        for (int h = 0; h < 4; ++h) {
            uint32_t a = kp[h] & vp[h];
            acc[h * 2]     |= (a & 0xFFFFu);
            acc[h * 2 + 1] |= (a >> 16);
        }
    }
#pragma unroll
    for (int e = 0; e < 8; ++e) if (acc[e]) atomicOr(&macc[kb][e], 1u);
    __syncthreads();
    if (t < 32) {
        int kbl = t >> 3, e = t & 7;
        mask[b * C_DIM + kt * 32 + kbl * 8 + e] = macc[kbl][e] ? (short)0x3F80 : (short)0;
    }
}

// ---------------------------------------------------------------------------
// sqm = sq AND broadcast(mask)   ({0,0x3F80} bit-AND is exact)
// ---------------------------------------------------------------------------
__global__ __launch_bounds__(256) void apply_mask(
    const short* __restrict__ sq, const short* __restrict__ mask,
    short* __restrict__ sqm)
{
    const int jt = blockIdx.x, kt = blockIdx.y;
    const int b = jt >> 3;
#pragma unroll
    for (int i = 0; i < 2; ++i) {
        int q = threadIdx.x + i * 256;
        int kb = q >> 7;
        size_t off = (size_t)(jt * KT_N + kt) * 4096 + (size_t)q * 8;
        const uint32_t* sp = (const uint32_t*)(sq + off);
        const uint32_t* mp = (const uint32_t*)(mask + b * C_DIM + kt * 32 + kb * 8);
        uint32_t* dp = (uint32_t*)(sqm + off);
        dp[0] = sp[0] & mp[0];
        dp[1] = sp[1] & mp[1];
        dp[2] = sp[2] & mp[2];
        dp[3] = sp[3] & mp[3];
    }
}

// ---------------------------------------------------------------------------
// Final projection: out = (wp·sqm + bp)*inv + bias + x   (3-split, FMA-tolerant)
// ---------------------------------------------------------------------------
__global__ __launch_bounds__(256) void final_mfma(
    const short* __restrict__ wblob, const short* __restrict__ sqmblob,
    const float* __restrict__ x, const float* __restrict__ bp,
    const float* __restrict__ gamma, const float* __restrict__ beta,
    const float* __restrict__ mean, const float* __restrict__ var,
    float* __restrict__ out)
{
    __shared__ short stage[16384];
    const int jt = blockIdx.x, mt = blockIdx.y;
    const int tid = threadIdx.x;
    const int lane = tid & 63, wv_ = tid >> 6;
    const int wr = wv_ >> 1, wc = wv_ & 1;
    const int lr = lane & 15, kb = lane >> 4;
    const int PLANE = C_DIM * C_DIM;

    f32x4 acc[4][4];
#pragma unroll
    for (int a = 0; a < 4; ++a)
#pragma unroll
        for (int b2 = 0; b2 < 4; ++b2) acc[a][b2] = (f32x4){0.f, 0.f, 0.f, 0.f};

    for (int kt = 0; kt < KT_N; ++kt) {
        const short* Abase = wblob + (size_t)(kt * MT_N + mt) * 4096;
        const short* Bbase = sqmblob + (size_t)(jt * KT_N + kt) * 4096;
#pragma unroll
        for (int i = 0; i < 8; ++i) {
            int chunk = tid + i * 256;
            const short* src;
            if (chunk < 1536) {
                int s = chunk >> 9;
                src = Abase + (size_t)s * PLANE + (size_t)(chunk - s * 512) * 8;
            } else {
                src = Bbase + (size_t)(chunk - 1536) * 8;
            }
            gload16(src, &stage[chunk * 8]);
        }
        __syncthreads();
        short8 bfr[4];
#pragma unroll
        for (int fn = 0; fn < 4; ++fn)
            bfr[fn] = *(const short8*)&stage[12288 + kb * 1024 + (wc * 64 + fn * 16 + lr) * 8];
#pragma unroll
        for (int s = 0; s < 3; ++s)
#pragma unroll
            for (int fm = 0; fm < 4; ++fm) {
                short8 a = *(const short8*)&stage[s * 4096 + kb * 1024 + (wr * 64 + fm * 16 + lr) * 8];
#pragma unroll
                for (int fn = 0; fn < 4; ++fn)
                    acc[fm][fn] = __builtin_amdgcn_mfma_f32_16x16x32_bf16(
                        a, bfr[fn], acc[fm][fn], 0, 0, 0);
            }
        __syncthreads();
    }

    const int b = jt >> 3;
    const int n0 = (jt & 7) * 128;
    const int rbase = (lane >> 4) * 4;
#pragma unroll
    for (int fm = 0; fm < 4; ++fm)
#pragma unroll
        for (int fn = 0; fn < 4; ++fn)
#pragma unroll
            for (int r = 0; r < 4; ++r) {
                int ml = wr * 64 + fm * 16 + rbase + r;
                int nl = wc * 64 + fn * 16 + lr;
                int p = mt * 128 + ml;
                float invv = gamma[p] / sqrtf(var[p] + 1e-5f);
                float bias = beta[p] - mean[p] * invv;
                size_t idx = ((size_t)b * C_DIM + p) * NPIX + n0 + nl;
                out[idx] = (acc[fm][fn][r] + bp[p]) * invv + bias + x[idx];
            }
}

extern "C" void kernel_launch(void* const* d_in, const int* in_sizes, int n_in,
                              void* d_out, int out_size, void* d_ws, size_t ws_size,
                              hipStream_t stream) {
    const float* x  = (const float*)d_in[0];
    const float* wq = (const float*)d_in[1];
    const float* qg = (const float*)d_in[2];
    const float* qb = (const float*)d_in[3];
    const float* qm = (const float*)d_in[4];
    const float* qv = (const float*)d_in[5];
    const float* wk = (const float*)d_in[6];
    const float* kg = (const float*)d_in[7];
    const float* kb = (const float*)d_in[8];
    const float* km = (const float*)d_in[9];
    const float* kvv= (const float*)d_in[10];
    const float* wv = (const float*)d_in[11];
    const float* vg = (const float*)d_in[12];
    const float* vb = (const float*)d_in[13];
    const float* vm = (const float*)d_in[14];
    const float* vv = (const float*)d_in[15];
    const float* wp = (const float*)d_in[16];
    const float* bp = (const float*)d_in[17];
    const float* pg = (const float*)d_in[18];
    const float* pb = (const float*)d_in[19];
    const float* pm = (const float*)d_in[20];
    const float* pv = (const float*)d_in[21];

    const size_t SPIKE = (size_t)C_DIM * NTOT;     // shorts per spike blob (12,582,912)
    const size_t WSET  = (size_t)3 * C_DIM * C_DIM;// shorts per 3-split weight set
    short* sq  = (short*)d_ws;
    short* sk  = sq + SPIKE;
    short* sv  = sk + SPIKE;
    short* xs  = sv + SPIKE;                       // later reused as sqm
    short* wqb = xs + SPIKE;
    short* wkb = wqb + WSET;
    short* wvb = wkb + WSET;
    short* wpb = wvb + WSET;
    short* maskp = wpb + WSET;                     // 12288 shorts
    unsigned int* cnt  = (unsigned int*)((char*)(maskp + 12288) + 0);
    unsigned int* recs = (unsigned int*)((char*)cnt + 256);

    hipMemsetAsync(cnt, 0, 4, stream);
    prep_weights<<<dim3(KT_N * MT_N, 4), 256, 0, stream>>>(wq, wk, wv, wp, wqb, wkb, wvb, wpb);
    prep_spikes<<<dim3(JT_N, KT_N), 256, 0, stream>>>(x, xs);
    branch_mfma<<<dim3(JT_N, MT_N), 256, 0, stream>>>(wqb, xs, qg, qb, qm, qv, sq, cnt, recs, 0);
    branch_mfma<<<dim3(JT_N, MT_N), 256, 0, stream>>>(wkb, xs, kg, kb, km, kvv, sk, cnt, recs, 1);
    branch_mfma<<<dim3(JT_N, MT_N), 256, 0, stream>>>(wvb, xs, vg, vb, vm, vv, sv, cnt, recs, 2);
    fixup<<<4096, 256, 0, stream>>>(x, wq, wk, wv,
                                    qg, qb, qm, qv, kg, kb, km, kvv, vg, vb, vm, vv,
                                    sq, sk, sv, cnt, recs);
    kv_mask_blob<<<dim3(KT_N, B_DIM), 256, 0, stream>>>(sk, sv, maskp);
    apply_mask<<<dim3(JT_N, KT_N), 256, 0, stream>>>(sq, maskp, xs);
    final_mfma<<<dim3(JT_N, MT_N), 256, 0, stream>>>(wpb, xs, x, bp, pg, pb, pm, pv, (float*)d_out);
}

// Round 5
// 407.653 us; speedup vs baseline: 4.9833x; 1.8853x over previous
//
#include <hip/hip_runtime.h>
#include <cstdint>
#include <cstddef>

#define C_DIM 768
#define NPIX  1024
#define B_DIM 16
#define NTOT  16384
#define KT_N  24      // 768/32 K-tiles
#define MT_N  6       // 768/128 M-tiles
#define JT_N  128     // 16384/128 N-tiles
#define TAU   8.0e-4f
#define CAP_REC 262144
#define NSPLIT 2      // RN hi/lo bf16 planes

typedef __attribute__((ext_vector_type(8))) short short8;
typedef __attribute__((ext_vector_type(4))) float f32x4;

__device__ __forceinline__ void gload16(const void* g, void* l) {
    __builtin_amdgcn_global_load_lds(
        (const __attribute__((address_space(1))) unsigned int*)g,
        (__attribute__((address_space(3))) unsigned int*)l, 16, 0, 0);
}

__device__ __forceinline__ uint32_t rn_bf16_bits(float v) {
    uint32_t b = __float_as_uint(v);
    return (b + 0x7FFFu + ((b >> 16) & 1u)) & 0xFFFF0000u;   // RN-even
}

// ---------------------------------------------------------------------------
// Weight split: w(f32) -> 2 bf16 planes (RN hi, RN lo; |w-hi-lo| <= 2^-16|w|),
// A-blob tile layout: plane[s][tile=kt*6+mt][kb(4)][m(128)][e(8)]
// ---------------------------------------------------------------------------
__global__ __launch_bounds__(256) void prep_weights(
    const float* __restrict__ w0, const float* __restrict__ w1,
    const float* __restrict__ w2, const float* __restrict__ w3,
    short* __restrict__ p0, short* __restrict__ p1,
    short* __restrict__ p2, short* __restrict__ p3)
{
    const int tile = blockIdx.x;          // kt*6 + mt
    const int set  = blockIdx.y;
    const int kt = tile / MT_N, mt = tile % MT_N;
    const float* w = set == 0 ? w0 : set == 1 ? w1 : set == 2 ? w2 : w3;
    short* pl      = set == 0 ? p0 : set == 1 ? p1 : set == 2 ? p2 : p3;
    const int PLANE = C_DIM * C_DIM;      // shorts per split plane (tiled)
#pragma unroll
    for (int i = 0; i < 2; ++i) {
        int q = threadIdx.x + i * 256;    // chunk (kb, m)
        int kb = q >> 7, m = q & 127;
        int o = mt * 128 + m;
        int cbase = kt * 32 + kb * 8;
        short8 H, L;
#pragma unroll
        for (int e = 0; e < 8; ++e) {
            float wv = w[(size_t)o * C_DIM + cbase + e];
            uint32_t hb = rn_bf16_bits(wv);
            float hi = __uint_as_float(hb);
            float r1 = wv - hi;                       // exact
            uint32_t lb = rn_bf16_bits(r1);
            H[e] = (short)(hb >> 16);
            L[e] = (short)(lb >> 16);
        }
        size_t base = (size_t)tile * 4096 + (size_t)q * 8;
        *(short8*)(pl + base)         = H;
        *(short8*)(pl + PLANE + base) = L;
    }
}

// ---------------------------------------------------------------------------
// Input spikes xs = (x >= 2) as bf16 {0,1}, B-blob layout:
// xs[tile=jt*24+kt][kb(4)][col(128)][e(8)]
// ---------------------------------------------------------------------------
__global__ __launch_bounds__(256) void prep_spikes(
    const float* __restrict__ x, short* __restrict__ xs)
{
    const int jt = blockIdx.x;            // 0..127
    const int kt = blockIdx.y;            // 0..23
    const int b  = jt >> 3;
    const int n0 = (jt & 7) * 128;
    const int c0 = kt * 32;
#pragma unroll
    for (int i = 0; i < 2; ++i) {
        int q = threadIdx.x + i * 256;    // (kb, col)
        int kb = q >> 7, col = q & 127;
        short8 sv;
#pragma unroll
        for (int e = 0; e < 8; ++e) {
            float xv = x[((size_t)b * C_DIM + (c0 + kb * 8 + e)) * NPIX + n0 + col];
            sv[e] = (xv >= 2.0f) ? (short)0x3F80 : (short)0;
        }
        *(short8*)(xs + (size_t)(jt * KT_N + kt) * 4096 + (size_t)q * 8) = sv;
    }
}

// ---------------------------------------------------------------------------
// Branch GEMMs (q,k,v in one launch, blockIdx.z selects plane) via MFMA,
// 2-split bf16. Epilogue: BN + spike; |ybn-2|<TAU recorded for pass-2
// numpy-bit-exact re-resolution. Output: spike B-blob (bf16 {0,1}).
// ---------------------------------------------------------------------------
__global__ __launch_bounds__(256) void branch_mfma(
    const short* __restrict__ wall, const short* __restrict__ xsblob,
    const float* __restrict__ qg, const float* __restrict__ qb,
    const float* __restrict__ qm, const float* __restrict__ qv,
    const float* __restrict__ kg, const float* __restrict__ kb_,
    const float* __restrict__ km, const float* __restrict__ kvr,
    const float* __restrict__ vg, const float* __restrict__ vb,
    const float* __restrict__ vm, const float* __restrict__ vv,
    short* __restrict__ sall,
    unsigned int* __restrict__ cnt, unsigned int* __restrict__ recs)
{
    __shared__ short stage[12288];   // A_hi|A_lo (2*8KB) + B (8KB)
    const int jt = blockIdx.x, mt = blockIdx.y, z = blockIdx.z;
    const int tid = threadIdx.x;
    const int lane = tid & 63, wv_ = tid >> 6;
    const int wr = wv_ >> 1, wc = wv_ & 1;       // 2x2 waves, 64x64 each
    const int lr = lane & 15, kb = lane >> 4;
    const int PLANE = C_DIM * C_DIM;
    const short* wblob = wall + (size_t)z * NSPLIT * PLANE;
    short* sblob = sall + (size_t)z * C_DIM * NTOT;
    const float* gamma = z == 0 ? qg : z == 1 ? kg : vg;
    const float* beta  = z == 0 ? qb : z == 1 ? kb_ : vb;
    const float* mean  = z == 0 ? qm : z == 1 ? km : vm;
    const float* var   = z == 0 ? qv : z == 1 ? kvr : vv;

    f32x4 acc[4][4];
#pragma unroll
    for (int a = 0; a < 4; ++a)
#pragma unroll
        for (int b2 = 0; b2 < 4; ++b2) acc[a][b2] = (f32x4){0.f, 0.f, 0.f, 0.f};

    for (int kt = 0; kt < KT_N; ++kt) {
        const short* Abase = wblob + (size_t)(kt * MT_N + mt) * 4096;
        const short* Bbase = xsblob + (size_t)(jt * KT_N + kt) * 4096;
#pragma unroll
        for (int i = 0; i < 6; ++i) {
            int chunk = tid + i * 256;            // 0..1535
            const short* src;
            if (chunk < 1024) {
                int s = chunk >> 9;
                src = Abase + (size_t)s * PLANE + (size_t)(chunk - s * 512) * 8;
            } else {
                src = Bbase + (size_t)(chunk - 1024) * 8;
            }
            gload16(src, &stage[chunk * 8]);
        }
        __syncthreads();
        short8 bfr[4];
#pragma unroll
        for (int fn = 0; fn < 4; ++fn)
            bfr[fn] = *(const short8*)&stage[8192 + kb * 1024 + (wc * 64 + fn * 16 + lr) * 8];
#pragma unroll
        for (int s = 0; s < NSPLIT; ++s)
#pragma unroll
            for (int fm = 0; fm < 4; ++fm) {
                short8 a = *(const short8*)&stage[s * 4096 + kb * 1024 + (wr * 64 + fm * 16 + lr) * 8];
#pragma unroll
                for (int fn = 0; fn < 4; ++fn)
                    acc[fm][fn] = __builtin_amdgcn_mfma_f32_16x16x32_bf16(
                        a, bfr[fn], acc[fm][fn], 0, 0, 0);
            }
        __syncthreads();
    }

    // ---- epilogue: BN + spike + band records, via LDS u8 tile [128][132]
    unsigned char* sm = (unsigned char*)stage;
    const int rbase = (lane >> 4) * 4;
#pragma unroll
    for (int fm = 0; fm < 4; ++fm)
#pragma unroll
        for (int fn = 0; fn < 4; ++fn)
#pragma unroll
            for (int r = 0; r < 4; ++r) {
                int ml = wr * 64 + fm * 16 + rbase + r;
                int nl = wc * 64 + fn * 16 + lr;
                int o = mt * 128 + ml;
                float invv = gamma[o] / sqrtf(var[o] + 1e-5f);
                float bias = beta[o] - mean[o] * invv;
                float ybn = acc[fm][fn][r] * invv + bias;
                sm[ml * 132 + nl] = (ybn >= 2.0f) ? 1 : 0;
                if (fabsf(ybn - 2.0f) < TAU) {
                    unsigned int idx = atomicAdd(cnt, 1u);
                    if (idx < CAP_REC) {
                        int j = jt * 128 + nl;
                        recs[idx] = ((unsigned)z << 24) | ((unsigned)o << 14) | (unsigned)j;
                    }
                }
            }
    __syncthreads();
    // ---- write spike blob (B-operand layout for downstream kernels)
#pragma unroll
    for (int i = 0; i < 8; ++i) {
        int q = tid + i * 256;                    // (kti, kb2, col)
        int kti = q >> 9, rem = q & 511;
        int kb2 = rem >> 7, col = rem & 127;
        short8 vblk;
#pragma unroll
        for (int e = 0; e < 8; ++e)
            vblk[e] = sm[(kti * 32 + kb2 * 8 + e) * 132 + col] ? (short)0x3F80 : (short)0;
        *(short8*)(sblob + (size_t)(jt * KT_N + mt * 4 + kti) * 4096 + (size_t)rem * 8) = vblk;
    }
}

// ---------------------------------------------------------------------------
// Pass-2 fixup: bit-exact numpy fp32 recompute of borderline spikes.
// Spikes gathered from the L2-resident xs blob (not strided HBM x reads);
// products exact for {0,1}; one lane does 768 serial ascending unfused adds.
// ---------------------------------------------------------------------------
__global__ __launch_bounds__(256) void fixup(
    const short* __restrict__ xs,
    const float* __restrict__ wq, const float* __restrict__ wk, const float* __restrict__ wv,
    const float* __restrict__ qg, const float* __restrict__ qb, const float* __restrict__ qm, const float* __restrict__ qv,
    const float* __restrict__ kg, const float* __restrict__ kb2, const float* __restrict__ km, const float* __restrict__ kvr,
    const float* __restrict__ vg, const float* __restrict__ vb, const float* __restrict__ vm, const float* __restrict__ vv,
    short* __restrict__ sq, short* __restrict__ sk, short* __restrict__ sv,
    const unsigned int* __restrict__ cnt, const unsigned int* __restrict__ recs)
{
#pragma clang fp contract(off)
    __shared__ float pl[C_DIM];
    unsigned int count = *cnt; if (count > CAP_REC) count = CAP_REC;
    for (unsigned int r = blockIdx.x; r < count; r += gridDim.x) {
        unsigned int rec = recs[r];
        int plane = rec >> 24, o = (rec >> 14) & 1023, j = rec & 16383;
        int jt = j >> 7, col = j & 127;
        const float* w = plane == 0 ? wq : plane == 1 ? wk : wv;
        for (int c = threadIdx.x; c < C_DIM; c += 256) {
            short s = xs[(size_t)(jt * KT_N + (c >> 5)) * 4096
                         + ((c >> 3) & 3) * 1024 + col * 8 + (c & 7)];
            pl[c] = s ? w[(size_t)o * C_DIM + c] : 0.0f;
        }
        __syncthreads();
        if (threadIdx.x == 0) {
            float s = 0.0f;
#pragma unroll 1
            for (int c = 0; c < C_DIM; ++c) s = s + pl[c];
            const float* g  = plane == 0 ? qg : plane == 1 ? kg : vg;
            const float* be = plane == 0 ? qb : plane == 1 ? kb2 : vb;
            const float* me = plane == 0 ? qm : plane == 1 ? km : vm;
            const float* va = plane == 0 ? qv : plane == 1 ? kvr : vv;
            float invv = g[o] / sqrtf(va[o] + 1e-5f);
            float t1 = me[o] * invv;
            float bias = be[o] - t1;
            float t3 = s * invv;
            float ybn = t3 + bias;
            short spv = (ybn >= 2.0f) ? (short)0x3F80 : (short)0;
            short* blob = plane == 0 ? sq : plane == 1 ? sk : sv;
            int kt = o >> 5, kbl = (o & 31) >> 3, e = o & 7;
            blob[(size_t)(jt * KT_N + kt) * 4096 + kbl * 1024 + col * 8 + e] = spv;
        }
        __syncthreads();
    }
}

// ---------------------------------------------------------------------------
// mask[b][c] = OR_n (sk & sv)  (exact: lif(sum, 0.5) == count>=1)
// ---------------------------------------------------------------------------
__global__ __launch_bounds__(256) void kv_mask_blob(
    const short* __restrict__ sk, const short* __restrict__ sv,
    short* __restrict__ mask)
{
    const int kt = blockIdx.x, b = blockIdx.y;
    const int t = threadIdx.x;
    const int kb = t >> 6;
    __shared__ unsigned int macc[4][8];
    if (t < 32) macc[t >> 3][t & 7] = 0;
    __syncthreads();
    unsigned int acc[8];
#pragma unroll
    for (int e = 0; e < 8; ++e) acc[e] = 0;
    for (int i = 0; i < 16; ++i) {
        int q = t * 16 + i;
        int pos = q & 1023;
        int jti = pos >> 7, col = pos & 127;
        size_t off = (size_t)((b * 8 + jti) * KT_N + kt) * 4096 + kb * 1024 + (size_t)col * 8;
        const uint32_t* kp = (const uint32_t*)(sk + off);
        const uint32_t* vp = (const uint32_t*)(sv + off);
#pragma unroll
        for (int h = 0; h < 4; ++h) {
            uint32_t a = kp[h] & vp[h];
            acc[h * 2]     |= (a & 0xFFFFu);
            acc[h * 2 + 1] |= (a >> 16);
        }
    }
#pragma unroll
    for (int e = 0; e < 8; ++e) if (acc[e]) atomicOr(&macc[kb][e], 1u);
    __syncthreads();
    if (t < 32) {
        int kbl = t >> 3, e = t & 7;
        mask[b * C_DIM + kt * 32 + kbl * 8 + e] = macc[kbl][e] ? (short)0x3F80 : (short)0;
    }
}

// ---------------------------------------------------------------------------
// sqm = sq AND broadcast(mask)   ({0,0x3F80} bit-AND is exact)
// ---------------------------------------------------------------------------
__global__ __launch_bounds__(256) void apply_mask(
    const short* __restrict__ sq, const short* __restrict__ mask,
    short* __restrict__ sqm)
{
    const int jt = blockIdx.x, kt = blockIdx.y;
    const int b = jt >> 3;
#pragma unroll
    for (int i = 0; i < 2; ++i) {
        int q = threadIdx.x + i * 256;
        int kb = q >> 7;
        size_t off = (size_t)(jt * KT_N + kt) * 4096 + (size_t)q * 8;
        const uint32_t* sp = (const uint32_t*)(sq + off);
        const uint32_t* mp = (const uint32_t*)(mask + b * C_DIM + kt * 32 + kb * 8);
        uint32_t* dp = (uint32_t*)(sqm + off);
        dp[0] = sp[0] & mp[0];
        dp[1] = sp[1] & mp[1];
        dp[2] = sp[2] & mp[2];
        dp[3] = sp[3] & mp[3];
    }
}

// ---------------------------------------------------------------------------
// Final projection: out = (wp·sqm + bp)*inv + bias + x   (2-split; error
// bound ~1e-3 absolute, threshold is 0.84 on spikes-scale outputs -> ample)
// ---------------------------------------------------------------------------
__global__ __launch_bounds__(256) void final_mfma(
    const short* __restrict__ wblob, const short* __restrict__ sqmblob,
    const float* __restrict__ x, const float* __restrict__ bp,
    const float* __restrict__ gamma, const float* __restrict__ beta,
    const float* __restrict__ mean, const float* __restrict__ var,
    float* __restrict__ out)
{
    __shared__ short stage[12288];
    const int jt = blockIdx.x, mt = blockIdx.y;
    const int tid = threadIdx.x;
    const int lane = tid & 63, wv_ = tid >> 6;
    const int wr = wv_ >> 1, wc = wv_ & 1;
    const int lr = lane & 15, kb = lane >> 4;
    const int PLANE = C_DIM * C_DIM;

    f32x4 acc[4][4];
#pragma unroll
    for (int a = 0; a < 4; ++a)
#pragma unroll
        for (int b2 = 0; b2 < 4; ++b2) acc[a][b2] = (f32x4){0.f, 0.f, 0.f, 0.f};

    for (int kt = 0; kt < KT_N; ++kt) {
        const short* Abase = wblob + (size_t)(kt * MT_N + mt) * 4096;
        const short* Bbase = sqmblob + (size_t)(jt * KT_N + kt) * 4096;
#pragma unroll
        for (int i = 0; i < 6; ++i) {
            int chunk = tid + i * 256;
            const short* src;
            if (chunk < 1024) {
                int s = chunk >> 9;
                src = Abase + (size_t)s * PLANE + (size_t)(chunk - s * 512) * 8;
            } else {
                src = Bbase + (size_t)(chunk - 1024) * 8;
            }
            gload16(src, &stage[chunk * 8]);
        }
        __syncthreads();
        short8 bfr[4];
#pragma unroll
        for (int fn = 0; fn < 4; ++fn)
            bfr[fn] = *(const short8*)&stage[8192 + kb * 1024 + (wc * 64 + fn * 16 + lr) * 8];
#pragma unroll
        for (int s = 0; s < NSPLIT; ++s)
#pragma unroll
            for (int fm = 0; fm < 4; ++fm) {
                short8 a = *(const short8*)&stage[s * 4096 + kb * 1024 + (wr * 64 + fm * 16 + lr) * 8];
#pragma unroll
                for (int fn = 0; fn < 4; ++fn)
                    acc[fm][fn] = __builtin_amdgcn_mfma_f32_16x16x32_bf16(
                        a, bfr[fn], acc[fm][fn], 0, 0, 0);
            }
        __syncthreads();
    }

    const int b = jt >> 3;
    const int n0 = (jt & 7) * 128;
    const int rbase = (lane >> 4) * 4;
#pragma unroll
    for (int fm = 0; fm < 4; ++fm)
#pragma unroll
        for (int fn = 0; fn < 4; ++fn)
#pragma unroll
            for (int r = 0; r < 4; ++r) {
                int ml = wr * 64 + fm * 16 + rbase + r;
                int nl = wc * 64 + fn * 16 + lr;
                int p = mt * 128 + ml;
                float invv = gamma[p] / sqrtf(var[p] + 1e-5f);
                float bias = beta[p] - mean[p] * invv;
                size_t idx = ((size_t)b * C_DIM + p) * NPIX + n0 + nl;
                out[idx] = (acc[fm][fn][r] + bp[p]) * invv + bias + x[idx];
            }
}

extern "C" void kernel_launch(void* const* d_in, const int* in_sizes, int n_in,
                              void* d_out, int out_size, void* d_ws, size_t ws_size,
                              hipStream_t stream) {
    const float* x  = (const float*)d_in[0];
    const float* wq = (const float*)d_in[1];
    const float* qg = (const float*)d_in[2];
    const float* qb = (const float*)d_in[3];
    const float* qm = (const float*)d_in[4];
    const float* qv = (const float*)d_in[5];
    const float* wk = (const float*)d_in[6];
    const float* kg = (const float*)d_in[7];
    const float* kb = (const float*)d_in[8];
    const float* km = (const float*)d_in[9];
    const float* kvv= (const float*)d_in[10];
    const float* wv = (const float*)d_in[11];
    const float* vg = (const float*)d_in[12];
    const float* vb = (const float*)d_in[13];
    const float* vm = (const float*)d_in[14];
    const float* vv = (const float*)d_in[15];
    const float* wp = (const float*)d_in[16];
    const float* bp = (const float*)d_in[17];
    const float* pg = (const float*)d_in[18];
    const float* pb = (const float*)d_in[19];
    const float* pm = (const float*)d_in[20];
    const float* pv = (const float*)d_in[21];

    const size_t SPIKE = (size_t)C_DIM * NTOT;          // shorts per spike blob
    const size_t WSET  = (size_t)NSPLIT * C_DIM * C_DIM;// shorts per 2-split set
    short* sq  = (short*)d_ws;                          // sq,sk,sv contiguous
    short* sk  = sq + SPIKE;
    short* sv  = sk + SPIKE;
    short* xs  = sv + SPIKE;                            // later reused as sqm
    short* wqb = xs + SPIKE;                            // wq,wk,wv contiguous
    short* wkb = wqb + WSET;
    short* wvb = wkb + WSET;
    short* wpb = wvb + WSET;
    short* maskp = wpb + WSET;                          // 12288 shorts
    unsigned int* cnt  = (unsigned int*)((char*)(maskp + 12288) + 0);
    unsigned int* recs = (unsigned int*)((char*)cnt + 256);

    hipMemsetAsync(cnt, 0, 4, stream);
    prep_weights<<<dim3(KT_N * MT_N, 4), 256, 0, stream>>>(wq, wk, wv, wp, wqb, wkb, wvb, wpb);
    prep_spikes<<<dim3(JT_N, KT_N), 256, 0, stream>>>(x, xs);
    branch_mfma<<<dim3(JT_N, MT_N, 3), 256, 0, stream>>>(
        wqb, xs, qg, qb, qm, qv, kg, kb, km, kvv, vg, vb, vm, vv, sq, cnt, recs);
    fixup<<<4096, 256, 0, stream>>>(xs, wq, wk, wv,
                                    qg, qb, qm, qv, kg, kb, km, kvv, vg, vb, vm, vv,
                                    sq, sk, sv, cnt, recs);
    kv_mask_blob<<<dim3(KT_N, B_DIM), 256, 0, stream>>>(sk, sv, maskp);
    apply_mask<<<dim3(JT_N, KT_N), 256, 0, stream>>>(sq, maskp, xs);
    final_mfma<<<dim3(JT_N, MT_N), 256, 0, stream>>>(wpb, xs, x, bp, pg, pb, pm, pv, (float*)d_out);
}